// Round 6
// baseline (318.640 us; speedup 1.0000x reference)
//
#include <hip/hip_runtime.h>
#include <hip/hip_bf16.h>

// Problem constants
#define BQ 8
#define NATOM 512
#define NFEAT 42
#define NNEIGH 100
#define H1 64
#define H2 32

// native clang vector (required by __builtin_nontemporal_load)
typedef float vf4 __attribute__((ext_vector_type(4)));

// ws layout (floats):
//   [0, 172368)            padded dE, shape (B, NATOM+1, NFEAT), row 0 per image zeroed
//   [172368, 172368+4096)  Ei in f32 (for Etot reduction)
#define WS_DE 0
#define WS_EI (BQ * (NATOM + 1) * NFEAT)

// ---------------------------------------------------------------- kernel 1
// one WAVE per atom; 4 atoms per 256-thread block; 1024 blocks.
// Weights LDS-staged once per block (type is block-uniform: 4 | 256).
// W0 rows padded 42->43 (odd -> conflict-free), W1 rows 64->65.
__global__ __launch_bounds__(256) void k_ei(
    const float* __restrict__ image,
    const float* __restrict__ W0, const float* __restrict__ b0,
    const float* __restrict__ W1, const float* __restrict__ b1,
    const float* __restrict__ W2, const float* __restrict__ b2,
    float* __restrict__ dE,          // padded (B, 513, 42) f32
    float* __restrict__ eiF,         // (B*512) f32
    float* __restrict__ outEi)       // f32 output Ei (B*512)
{
    __shared__ float W0s[H1 * 43];
    __shared__ float W1s[H2 * 65];
    __shared__ float W2s[H2];
    __shared__ float b0s[H1];
    __shared__ float b1s[H2];
    __shared__ float xs[4][44];
    __shared__ float h0s[4][H1];
    __shared__ float g1s[4][H2];
    __shared__ float g0s[4][H1];

    const int tid  = threadIdx.x;
    const int w    = tid >> 6;            // wave id 0..3
    const int lane = tid & 63;
    const int ga   = blockIdx.x * 4 + w;  // global atom 0..4095
    const int b    = ga >> 9;
    const int t    = (blockIdx.x >> 6) & 1;   // type, block-uniform

    for (int e = tid; e < H1 * NFEAT; e += 256) {
        int r = e / NFEAT, c = e - r * NFEAT;
        W0s[r * 43 + c] = W0[t * (H1 * NFEAT) + e];
    }
    for (int e = tid; e < H2 * H1; e += 256) {
        int r = e >> 6, c = e & 63;
        W1s[r * 65 + c] = W1[t * (H2 * H1) + e];
    }
    if (tid < H2) { W2s[tid] = W2[t * H2 + tid]; b1s[tid] = b1[t * H2 + tid]; }
    if (tid >= 64 && tid < 128) b0s[tid - 64] = b0[t * H1 + (tid - 64)];
    if (lane < NFEAT) xs[w][lane] = image[(size_t)ga * NFEAT + lane];
    __syncthreads();

    // layer 1: lane j computes h0[j]
    float s = b0s[lane];
    #pragma unroll
    for (int f = 0; f < NFEAT; ++f) s = fmaf(W0s[lane * 43 + f], xs[w][f], s);
    const float h0 = tanhf(s);
    h0s[w][lane] = h0;
    __syncthreads();

    // layer 2: lane k (both half-waves compute k = lane&31 redundantly)
    const int k = lane & 31;
    s = b1s[k];
    #pragma unroll
    for (int j = 0; j < H1; ++j) s = fmaf(W1s[k * 65 + j], h0s[w][j], s);
    const float h1 = tanhf(s);

    // y = sum_k W2[k]*h1[k] (reduce lower 32 lanes)
    float p = W2s[k] * h1;
    p += __shfl_down(p, 16, 64);
    p += __shfl_down(p, 8, 64);
    p += __shfl_down(p, 4, 64);
    p += __shfl_down(p, 2, 64);
    p += __shfl_down(p, 1, 64);
    if (lane == 0) {
        float y = p + b2[t];
        eiF[ga]   = y;
        outEi[ga] = y;
    }

    // backward
    const float g1 = W2s[k] * (1.0f - h1 * h1);
    if (lane < H2) g1s[w][lane] = g1;
    __syncthreads();

    s = 0.0f;
    #pragma unroll
    for (int kk = 0; kk < H2; ++kk) s = fmaf(g1s[w][kk], W1s[kk * 65 + lane], s);
    const float g0 = s * (1.0f - h0 * h0);
    g0s[w][lane] = g0;
    __syncthreads();

    if (lane < NFEAT) {
        s = 0.0f;
        #pragma unroll
        for (int j = 0; j < H1; ++j) s = fmaf(g0s[w][j], W0s[j * 43 + lane], s);
        dE[((size_t)b * (NATOM + 1) + (ga & 511) + 1) * NFEAT + lane] = s;
    }

    if ((blockIdx.x & 127) == 0 && tid < NFEAT)
        dE[(size_t)(blockIdx.x >> 7) * (NATOM + 1) * NFEAT + tid] = 0.0f;
}

// ---------------------------------------------------------------- kernel 2
// one block per (b, atom). All 15 dfeat dwordx4 loads issued BEFORE the
// gather, so the barrier's vmcnt drain overlaps HBM stream with L2 gather.
__global__ __launch_bounds__(256) void k_force(
    const float* __restrict__ dfeat,
    const int* __restrict__ neighbor,
    const float* __restrict__ dE,
    const float* __restrict__ eiF,
    float* __restrict__ out)         // f32 output buffer, 16392 elems
{
    __shared__ __align__(16) float g[NNEIGH * NFEAT];   // 4200 f32 = 16.8 KB
    __shared__ int nb[NNEIGH];
    __shared__ float red[12];

    const int ba  = blockIdx.x;          // 0..4095
    const int b   = ba >> 9;
    const int tid = threadIdx.x;

    if (tid < NNEIGH) nb[tid] = neighbor[(size_t)ba * NNEIGH + tid];
    __syncthreads();

    // ---- issue ALL dfeat loads (independent of LDS) -------------------
    // 1050 chunks of 12 floats; chunks 0..1023 unconditionally (4/thread),
    // chunks 1024..1049 on threads 0..25.
    const float* __restrict__ df = dfeat + (size_t)ba * (NNEIGH * NFEAT * 3);
    vf4 v0[5], v1[5], v2[5];
    #pragma unroll
    for (int it = 0; it < 4; ++it) {
        const vf4* p = (const vf4*)(df + (size_t)(tid + it * 256) * 12);
        v0[it] = __builtin_nontemporal_load(p);
        v1[it] = __builtin_nontemporal_load(p + 1);
        v2[it] = __builtin_nontemporal_load(p + 2);
    }
    const bool tail = tid < (1050 - 1024);
    if (tail) {
        const vf4* p = (const vf4*)(df + (size_t)(tid + 1024) * 12);
        v0[4] = __builtin_nontemporal_load(p);
        v1[4] = __builtin_nontemporal_load(p + 1);
        v2[4] = __builtin_nontemporal_load(p + 2);
    }

    // ---- gather dE rows of the 100 neighbors into LDS (overlaps above)
    const float* __restrict__ dEb = dE + (size_t)b * (NATOM + 1) * NFEAT;
    for (int e = tid; e < NNEIGH * NFEAT; e += 256) {
        int n = e / NFEAT;
        int f = e - n * NFEAT;
        g[e] = dEb[(size_t)nb[n] * NFEAT + f];
    }
    __syncthreads();

    // ---- FMA phase: chunk gi pairs 4 g values with 12 dfeat floats ----
    const vf4* __restrict__ g4 = (const vf4*)g;
    float a0 = 0.f, a1 = 0.f, a2 = 0.f;
    #pragma unroll
    for (int it = 0; it < 4; ++it) {
        vf4 gv = g4[tid + it * 256];
        vf4 w0 = v0[it], w1 = v1[it], w2 = v2[it];
        a0 = fmaf(gv.x, w0.x, a0); a1 = fmaf(gv.x, w0.y, a1); a2 = fmaf(gv.x, w0.z, a2);
        a0 = fmaf(gv.y, w0.w, a0); a1 = fmaf(gv.y, w1.x, a1); a2 = fmaf(gv.y, w1.y, a2);
        a0 = fmaf(gv.z, w1.z, a0); a1 = fmaf(gv.z, w1.w, a1); a2 = fmaf(gv.z, w2.x, a2);
        a0 = fmaf(gv.w, w2.y, a0); a1 = fmaf(gv.w, w2.z, a1); a2 = fmaf(gv.w, w2.w, a2);
    }
    if (tail) {
        vf4 gv = g4[tid + 1024];
        vf4 w0 = v0[4], w1 = v1[4], w2 = v2[4];
        a0 = fmaf(gv.x, w0.x, a0); a1 = fmaf(gv.x, w0.y, a1); a2 = fmaf(gv.x, w0.z, a2);
        a0 = fmaf(gv.y, w0.w, a0); a1 = fmaf(gv.y, w1.x, a1); a2 = fmaf(gv.y, w1.y, a2);
        a0 = fmaf(gv.z, w1.z, a0); a1 = fmaf(gv.z, w1.w, a1); a2 = fmaf(gv.z, w2.x, a2);
        a0 = fmaf(gv.w, w2.y, a0); a1 = fmaf(gv.w, w2.z, a1); a2 = fmaf(gv.w, w2.w, a2);
    }

    // wave shuffle reduce (width 64), then cross-wave via LDS
    #pragma unroll
    for (int off = 32; off > 0; off >>= 1) {
        a0 += __shfl_down(a0, off, 64);
        a1 += __shfl_down(a1, off, 64);
        a2 += __shfl_down(a2, off, 64);
    }
    const int wave = tid >> 6, lane = tid & 63;
    if (lane == 0) { red[wave * 3] = a0; red[wave * 3 + 1] = a1; red[wave * 3 + 2] = a2; }
    __syncthreads();
    if (tid < 3) {
        float s = red[tid] + red[3 + tid] + red[6 + tid] + red[9 + tid];
        out[8 + BQ * NATOM + (size_t)ba * 3 + tid] = s;
    }

    // block 0 additionally reduces Etot (8 values) from f32 Ei in ws
    if (blockIdx.x == 0) {
        for (int bb = wave * 2; bb < wave * 2 + 2; ++bb) {
            float s = 0.f;
            for (int i = lane; i < NATOM; i += 64) s += eiF[bb * NATOM + i];
            #pragma unroll
            for (int off = 32; off > 0; off >>= 1) s += __shfl_down(s, off, 64);
            if (lane == 0) out[bb] = s;
        }
    }
}

// ---------------------------------------------------------------- launcher
extern "C" void kernel_launch(void* const* d_in, const int* in_sizes, int n_in,
                              void* d_out, int out_size, void* d_ws, size_t ws_size,
                              hipStream_t stream)
{
    const float* image    = (const float*)d_in[0];
    const float* dfeat    = (const float*)d_in[1];
    const int*   neighbor = (const int*)d_in[2];
    // d_in[3] natoms_img unused
    const float* W0 = (const float*)d_in[4];
    const float* b0 = (const float*)d_in[5];
    const float* W1 = (const float*)d_in[6];
    const float* b1 = (const float*)d_in[7];
    const float* W2 = (const float*)d_in[8];
    const float* b2 = (const float*)d_in[9];

    float* wsf  = (float*)d_ws;
    float* dE   = wsf + WS_DE;
    float* eiF  = wsf + WS_EI;
    float* out  = (float*)d_out;

    hipLaunchKernelGGL(k_ei, dim3(1024), dim3(256), 0, stream,
                       image, W0, b0, W1, b1, W2, b2, dE, eiF, out + 8);
    hipLaunchKernelGGL(k_force, dim3(4096), dim3(256), 0, stream,
                       dfeat, neighbor, dE, eiF, out);
}

// Round 7
// 296.385 us; speedup vs baseline: 1.0751x; 1.0751x over previous
//
#include <hip/hip_runtime.h>
#include <hip/hip_bf16.h>

// Problem constants
#define BQ 8
#define NATOM 512
#define NFEAT 42
#define NNEIGH 100
#define H1 64
#define H2 32

// native clang vector (required by __builtin_nontemporal_load)
typedef float vf4 __attribute__((ext_vector_type(4)));

// ws layout (floats):
//   [0, 172368)            padded dE, shape (B, NATOM+1, NFEAT), row 0 per image zeroed
//   [172368, 172368+4096)  Ei in f32 (for Etot reduction)
#define WS_DE 0
#define WS_EI (BQ * (NATOM + 1) * NFEAT)

// ---------------------------------------------------------------- kernel 1
// one WAVE per atom; 4 atoms per 256-thread block; 1024 blocks.
__global__ __launch_bounds__(256) void k_ei(
    const float* __restrict__ image,
    const float* __restrict__ W0, const float* __restrict__ b0,
    const float* __restrict__ W1, const float* __restrict__ b1,
    const float* __restrict__ W2, const float* __restrict__ b2,
    float* __restrict__ dE,          // padded (B, 513, 42) f32
    float* __restrict__ eiF,         // (B*512) f32
    float* __restrict__ outEi)       // f32 output Ei (B*512)
{
    __shared__ float W0s[H1 * 43];
    __shared__ float W1s[H2 * 65];
    __shared__ float W2s[H2];
    __shared__ float b0s[H1];
    __shared__ float b1s[H2];
    __shared__ float xs[4][44];
    __shared__ float h0s[4][H1];
    __shared__ float g1s[4][H2];
    __shared__ float g0s[4][H1];

    const int tid  = threadIdx.x;
    const int w    = tid >> 6;            // wave id 0..3
    const int lane = tid & 63;
    const int ga   = blockIdx.x * 4 + w;  // global atom 0..4095
    const int b    = ga >> 9;
    const int t    = (blockIdx.x >> 6) & 1;   // type, block-uniform

    for (int e = tid; e < H1 * NFEAT; e += 256) {
        int r = e / NFEAT, c = e - r * NFEAT;
        W0s[r * 43 + c] = W0[t * (H1 * NFEAT) + e];
    }
    for (int e = tid; e < H2 * H1; e += 256) {
        int r = e >> 6, c = e & 63;
        W1s[r * 65 + c] = W1[t * (H2 * H1) + e];
    }
    if (tid < H2) { W2s[tid] = W2[t * H2 + tid]; b1s[tid] = b1[t * H2 + tid]; }
    if (tid >= 64 && tid < 128) b0s[tid - 64] = b0[t * H1 + (tid - 64)];
    if (lane < NFEAT) xs[w][lane] = image[(size_t)ga * NFEAT + lane];
    __syncthreads();

    // layer 1: lane j computes h0[j]
    float s = b0s[lane];
    #pragma unroll
    for (int f = 0; f < NFEAT; ++f) s = fmaf(W0s[lane * 43 + f], xs[w][f], s);
    const float h0 = tanhf(s);
    h0s[w][lane] = h0;
    __syncthreads();

    // layer 2: lane k (both half-waves compute k = lane&31 redundantly)
    const int k = lane & 31;
    s = b1s[k];
    #pragma unroll
    for (int j = 0; j < H1; ++j) s = fmaf(W1s[k * 65 + j], h0s[w][j], s);
    const float h1 = tanhf(s);

    // y = sum_k W2[k]*h1[k] (reduce lower 32 lanes)
    float p = W2s[k] * h1;
    p += __shfl_down(p, 16, 64);
    p += __shfl_down(p, 8, 64);
    p += __shfl_down(p, 4, 64);
    p += __shfl_down(p, 2, 64);
    p += __shfl_down(p, 1, 64);
    if (lane == 0) {
        float y = p + b2[t];
        eiF[ga]   = y;
        outEi[ga] = y;
    }

    // backward
    const float g1 = W2s[k] * (1.0f - h1 * h1);
    if (lane < H2) g1s[w][lane] = g1;
    __syncthreads();

    s = 0.0f;
    #pragma unroll
    for (int kk = 0; kk < H2; ++kk) s = fmaf(g1s[w][kk], W1s[kk * 65 + lane], s);
    const float g0 = s * (1.0f - h0 * h0);
    g0s[w][lane] = g0;
    __syncthreads();

    if (lane < NFEAT) {
        s = 0.0f;
        #pragma unroll
        for (int j = 0; j < H1; ++j) s = fmaf(g0s[w][j], W0s[j * 43 + lane], s);
        dE[((size_t)b * (NATOM + 1) + (ga & 511) + 1) * NFEAT + lane] = s;
    }

    if ((blockIdx.x & 127) == 0 && tid < NFEAT)
        dE[(size_t)(blockIdx.x >> 7) * (NATOM + 1) * NFEAT + tid] = 0.0f;
}

// ---------------------------------------------------------------- kernel 2
// one block per (b, atom). dfeat streamed with FULLY COALESCED float4 loads
// (lane stride 16 B). Mod-3 pair/component misalignment handled statically:
// float4 j needs g[q], g[q+1] with q = j + j/3; product i uses g[q] iff
// i < 3 - (j%3); accumulator target rotates as (k+i)%3, un-rotated by tid%3.
__global__ __launch_bounds__(256) void k_force(
    const float* __restrict__ dfeat,
    const int* __restrict__ neighbor,
    const float* __restrict__ dE,
    const float* __restrict__ eiF,
    float* __restrict__ out)         // f32 output buffer, 16392 elems
{
    __shared__ float g[NNEIGH * NFEAT];   // 4200 f32 = 16.8 KB
    __shared__ int nb[NNEIGH];
    __shared__ float red[12];

    const int ba  = blockIdx.x;          // 0..4095
    const int b   = ba >> 9;
    const int tid = threadIdx.x;

    if (tid < NNEIGH) nb[tid] = neighbor[(size_t)ba * NNEIGH + tid];
    __syncthreads();

    // gather dE rows of the 100 neighbors into LDS (flat [n*42+f])
    const float* __restrict__ dEb = dE + (size_t)b * (NATOM + 1) * NFEAT;
    for (int e = tid; e < NNEIGH * NFEAT; e += 256) {
        int n = e / NFEAT;
        int f = e - n * NFEAT;
        g[e] = dEb[(size_t)nb[n] * NFEAT + f];
    }
    __syncthreads();

    // ---- per-lane mod-3 precompute (period 3 in the unrolled k) ----
    const int tid3 = tid % 3;
    int  qm[3];
    bool sel1[3], sel2[3];
    #pragma unroll
    for (int m = 0; m < 3; ++m) {
        int j = tid + 256 * m;
        int r = (tid3 + m) % 3;           // == j % 3 since 256 % 3 == 1
        qm[m]   = j + (j - r) / 3;        // q = j + floor(j/3)
        sel1[m] = (r < 2);                // product i=1 uses g[q] ?
        sel2[m] = (r == 0);               // product i=2 uses g[q] ?
    }

    // ---- stream: 3150 float4 per block; 12 full rounds + 78-thread tail
    const float* __restrict__ df = dfeat + (size_t)ba * (NNEIGH * NFEAT * 3);
    const vf4* __restrict__ df4 = (const vf4*)df;

    float c0 = 0.f, c1 = 0.f, c2 = 0.f;
    #pragma unroll
    for (int k = 0; k < 12; ++k) {
        const int m = k % 3;
        vf4 v = __builtin_nontemporal_load(df4 + tid + 256 * k);
        int q = qm[m] + (k / 3) * 1024;
        float gq = g[q], gq1 = g[q + 1];
        float s1 = sel1[m] ? gq : gq1;
        float s2 = sel2[m] ? gq : gq1;
        float p0 = gq * v.x, p1 = s1 * v.y, p2 = s2 * v.z, p3 = gq1 * v.w;
        if (m == 0) { c0 += p0; c1 += p1; c2 += p2; c0 += p3; }
        if (m == 1) { c1 += p0; c2 += p1; c0 += p2; c1 += p3; }
        if (m == 2) { c2 += p0; c0 += p1; c1 += p2; c2 += p3; }
    }
    if (tid < 3150 - 3072) {   // tail round k=12 (m=0)
        vf4 v = __builtin_nontemporal_load(df4 + tid + 3072);
        int q = qm[0] + 4096;
        float gq = g[q], gq1 = g[q + 1];
        float s1 = sel1[0] ? gq : gq1;
        float s2 = sel2[0] ? gq : gq1;
        c0 += gq * v.x; c1 += s1 * v.y; c2 += s2 * v.z; c0 += gq1 * v.w;
    }

    // un-rotate: c_m holds force component (tid3 + m) % 3
    float a0, a1, a2;
    if (tid3 == 0)      { a0 = c0; a1 = c1; a2 = c2; }
    else if (tid3 == 1) { a1 = c0; a2 = c1; a0 = c2; }
    else                { a2 = c0; a0 = c1; a1 = c2; }

    // wave shuffle reduce (width 64), then cross-wave via LDS
    #pragma unroll
    for (int off = 32; off > 0; off >>= 1) {
        a0 += __shfl_down(a0, off, 64);
        a1 += __shfl_down(a1, off, 64);
        a2 += __shfl_down(a2, off, 64);
    }
    const int wave = tid >> 6, lane = tid & 63;
    if (lane == 0) { red[wave * 3] = a0; red[wave * 3 + 1] = a1; red[wave * 3 + 2] = a2; }
    __syncthreads();
    if (tid < 3) {
        float s = red[tid] + red[3 + tid] + red[6 + tid] + red[9 + tid];
        out[8 + BQ * NATOM + (size_t)ba * 3 + tid] = s;
    }

    // block 0 additionally reduces Etot (8 values) from f32 Ei in ws
    if (blockIdx.x == 0) {
        for (int bb = wave * 2; bb < wave * 2 + 2; ++bb) {
            float s = 0.f;
            for (int i = lane; i < NATOM; i += 64) s += eiF[bb * NATOM + i];
            #pragma unroll
            for (int off = 32; off > 0; off >>= 1) s += __shfl_down(s, off, 64);
            if (lane == 0) out[bb] = s;
        }
    }
}

// ---------------------------------------------------------------- launcher
extern "C" void kernel_launch(void* const* d_in, const int* in_sizes, int n_in,
                              void* d_out, int out_size, void* d_ws, size_t ws_size,
                              hipStream_t stream)
{
    const float* image    = (const float*)d_in[0];
    const float* dfeat    = (const float*)d_in[1];
    const int*   neighbor = (const int*)d_in[2];
    // d_in[3] natoms_img unused
    const float* W0 = (const float*)d_in[4];
    const float* b0 = (const float*)d_in[5];
    const float* W1 = (const float*)d_in[6];
    const float* b1 = (const float*)d_in[7];
    const float* W2 = (const float*)d_in[8];
    const float* b2 = (const float*)d_in[9];

    float* wsf  = (float*)d_ws;
    float* dE   = wsf + WS_DE;
    float* eiF  = wsf + WS_EI;
    float* out  = (float*)d_out;

    hipLaunchKernelGGL(k_ei, dim3(1024), dim3(256), 0, stream,
                       image, W0, b0, W1, b1, W2, b2, dE, eiF, out + 8);
    hipLaunchKernelGGL(k_force, dim3(4096), dim3(256), 0, stream,
                       dfeat, neighbor, dE, eiF, out);
}